// Round 1
// 636.742 us; speedup vs baseline: 1.3181x; 1.3181x over previous
//
#include <hip/hip_runtime.h>
#include <math.h>

#define GROUPS 32
#define CG 16
#define HH 56
#define WW 56
#define HW (HH*WW)          // 3136
#define BG 1024             // B*GROUPS
#define EPS 1e-5f

#define RB 8                // output rows per band
#define NB 7                // bands per instance (RB*NB == HH)
#define LROW 64             // padded LDS row stride (floats); data at [4..59]

// ---------------------------------------------------------------------------
// Kernel A: per-instance directional pooling -> 1x1 channel mix -> sigmoid
// gates (xh, xw); per-channel mean/var of t = gx*xh*xw; analytic x2sum
// (spatial sum of SAME-pad 3x3 conv from row/col sums). New in this version:
//  - float4-vectorized row-mean, col-mean and sum/sumsq passes
//  - a2 = softmax(x2sum/HW) computed HERE (shfl over first 16 lanes) and
//    folded: ws_asc[c] = a2[c]*scale[c], ws_aofs = sum_c a2[c]*shift[c]
//  - block 0 additionally computes the (instance-independent) a1-folded
//    conv weights wa[ci][k] = sum_o softmax(gn_b)[o]*w3[o][ci][k] and
//    ab = sum_o softmax(gn_b)[o]*b3[o], stored once in ws_wa[145].
// One block per bg-instance.
// ---------------------------------------------------------------------------
__global__ __launch_bounds__(256) void kA(const float* __restrict__ x,
        const float* __restrict__ w1, const float* __restrict__ b1,
        const float* __restrict__ w3, const float* __restrict__ b3,
        const float* __restrict__ gn_w, const float* __restrict__ gn_b,
        float* __restrict__ ws_xh, float* __restrict__ ws_xw,
        float* __restrict__ ws_asc, float* __restrict__ ws_aofs,
        float* __restrict__ ws_wa)
{
    const int g = blockIdx.x;
    const int tid = threadIdx.x;
    const float* gx = x + (size_t)g * CG * HW;

    __shared__ float s_row[CG][HH];   // row means per channel
    __shared__ float s_col[CG][WW];   // col means per channel
    __shared__ float s_xh[CG][HH];    // sigmoid gate over rows
    __shared__ float s_xw[CG][WW];    // sigmoid gate over cols
    __shared__ float ls1[CG], ls2[CG];
    __shared__ float s_x2[CG];

    // one-time: a1-folded conv weights (a1 = softmax(gn_b), same for all g)
    if (g == 0 && tid < CG * 9 + 1) {
        float m = gn_b[0];
        #pragma unroll
        for (int c = 1; c < CG; ++c) m = fmaxf(m, gn_b[c]);
        float a1[CG]; float den = 0.f;
        #pragma unroll
        for (int c = 0; c < CG; ++c) { a1[c] = __expf(gn_b[c] - m); den += a1[c]; }
        float inv = 1.f / den;
        if (tid < CG * 9) {
            int ci = tid / 9, k = tid - (tid / 9) * 9;
            float s = 0.f;
            #pragma unroll
            for (int o = 0; o < CG; ++o) s += a1[o] * w3[(size_t)(o * CG + ci) * 9 + k];
            ws_wa[tid] = s * inv;
        } else {
            float s = 0.f;
            #pragma unroll
            for (int o = 0; o < CG; ++o) s += a1[o] * b3[o];
            ws_wa[CG * 9] = s * inv;
        }
    }

    // row means: task = (c, row); 14 coalesced-per-thread float4 loads
    for (int t = tid; t < CG * HH; t += 256) {
        int c = t / HH, r = t - (t / HH) * HH;
        const float4* p = (const float4*)(gx + c * HW + r * WW);
        float s = 0.f;
        #pragma unroll
        for (int i = 0; i < WW / 4; ++i) {
            float4 v = p[i];
            s += (v.x + v.y) + (v.z + v.w);
        }
        s_row[c][r] = s * (1.0f / WW);
    }
    // col means: task = (c, 4-col group); float4 rows, 4 accumulators
    for (int t = tid; t < CG * (WW / 4); t += 256) {
        int c = t / (WW / 4), q = t - (t / (WW / 4)) * (WW / 4);
        const float* p = gx + c * HW + q * 4;
        float a0 = 0.f, a1c = 0.f, a2c = 0.f, a3 = 0.f;
        #pragma unroll 8
        for (int i = 0; i < HH; ++i) {
            float4 v = *(const float4*)(p + i * WW);
            a0 += v.x; a1c += v.y; a2c += v.z; a3 += v.w;
        }
        s_col[c][q * 4 + 0] = a0  * (1.0f / HH);
        s_col[c][q * 4 + 1] = a1c * (1.0f / HH);
        s_col[c][q * 4 + 2] = a2c * (1.0f / HH);
        s_col[c][q * 4 + 3] = a3  * (1.0f / HH);
    }
    __syncthreads();

    // 1x1 conv (16x16 channel mix) + bias + sigmoid
    for (int t = tid; t < 2 * CG * HH; t += 256) {
        int hpart = (t < CG * HH);
        int tt = hpart ? t : t - CG * HH;
        int o = tt / HH, i = tt - (tt / HH) * HH;
        float v = b1[o];
        #pragma unroll
        for (int c = 0; c < CG; ++c)
            v += w1[o * CG + c] * (hpart ? s_row[c][i] : s_col[c][i]);
        float sg = 1.f / (1.f + __expf(-v));
        if (hpart) { s_xh[o][i] = sg; ws_xh[(size_t)g * CG * HH + tt] = sg; }
        else       { s_xw[o][i] = sg; ws_xw[(size_t)g * CG * WW + tt] = sg; }
    }

    // analytic x2sum: thread o computes spatial sum of conv output channel o
    if (tid < CG) {
        ls1[tid] = 0.f; ls2[tid] = 0.f;
        const int o = tid;
        float acc = (float)HW * b3[o];
        for (int c = 0; c < CG; ++c) {
            float S = 0.f;
            #pragma unroll
            for (int r = 0; r < HH; ++r) S += s_row[c][r];
            S *= (float)WW;
            float R0 = (float)WW * s_row[c][HH - 1];
            float R2 = (float)WW * s_row[c][0];
            float C0 = (float)HH * s_col[c][WW - 1];
            float C2 = (float)HH * s_col[c][0];
            const float* p = gx + c * HW;
            float e00 = p[0], e0N = p[WW - 1];
            float eN0 = p[(HH - 1) * WW], eNN = p[(HH - 1) * WW + WW - 1];
            const float* wp = w3 + (size_t)(o * CG + c) * 9;
            #pragma unroll
            for (int dy = 0; dy < 3; ++dy) {
                float Rv = (dy == 0) ? R0 : (dy == 2 ? R2 : 0.f);
                #pragma unroll
                for (int dx = 0; dx < 3; ++dx) {
                    float Cv = (dx == 0) ? C0 : (dx == 2 ? C2 : 0.f);
                    float T = S - Rv - Cv;
                    if (dy != 1 && dx != 1)
                        T += (dy == 0) ? ((dx == 0) ? eNN : eN0)
                                       : ((dx == 0) ? e0N : e00);
                    acc += wp[dy * 3 + dx] * T;
                }
            }
        }
        s_x2[tid] = acc;
    }
    __syncthreads();

    // per-channel sum / sumsq of t = gx * xh * xw (float4)
    for (int c = 0; c < CG; ++c) {
        float s1 = 0.f, s2 = 0.f;
        const float4* p = (const float4*)(gx + c * HW);
        float xwc0, xwc1, xwc2, xwc3;
        for (int idx = tid; idx < HW / 4; idx += 256) {
            int l = idx * 4;
            int yy = l / WW, xb = l - yy * WW;   // 56 % 4 == 0: no row cross
            float4 v = p[idx];
            float xh = s_xh[c][yy];
            xwc0 = s_xw[c][xb];     xwc1 = s_xw[c][xb + 1];
            xwc2 = s_xw[c][xb + 2]; xwc3 = s_xw[c][xb + 3];
            float t0 = v.x * xh * xwc0;
            float t1 = v.y * xh * xwc1;
            float t2 = v.z * xh * xwc2;
            float t3 = v.w * xh * xwc3;
            s1 += (t0 + t1) + (t2 + t3);
            s2 += (t0 * t0 + t1 * t1) + (t2 * t2 + t3 * t3);
        }
        #pragma unroll
        for (int off = 32; off; off >>= 1) {
            s1 += __shfl_down(s1, off);
            s2 += __shfl_down(s2, off);
        }
        if ((tid & 63) == 0) {
            atomicAdd(&ls1[c], s1);
            atomicAdd(&ls2[c], s2);
        }
    }
    __syncthreads();

    // scale/shift -> fold with a2 = softmax(x2sum/HW)  (lanes 0..15, wave 0)
    if (tid < CG) {
        float mu  = ls1[tid] * (1.0f / HW);
        float var = ls2[tid] * (1.0f / HW) - mu * mu;
        float sc  = gn_w[tid] * rsqrtf(var + EPS);
        float sh  = gn_b[tid] - mu * sc;

        float v2 = s_x2[tid] * (1.0f / HW);
        float m = v2;
        #pragma unroll
        for (int off = 8; off; off >>= 1) m = fmaxf(m, __shfl_xor(m, off));
        float e = __expf(v2 - m);
        float den = e;
        #pragma unroll
        for (int off = 8; off; off >>= 1) den += __shfl_xor(den, off);
        float a2 = e / den;

        ws_asc[(size_t)g * CG + tid] = a2 * sc;
        float part = a2 * sh;
        #pragma unroll
        for (int off = 8; off; off >>= 1) part += __shfl_xor(part, off);
        if (tid == 0) ws_aofs[g] = part;
    }
}

// ---------------------------------------------------------------------------
// Kernel BC (fused former kB2 + kC): one block per (instance, 8-row band).
// Stage the band (16 ch x 10 rows incl. halo, zero-padded cols) in LDS with
// coalesced float4 loads; compute the a1-folded 3x3 conv AND the final
// epilogue out = gx * sigmoid(conv + ab + aofs + sum_c asc[c]*xh*xw*gx)
// entirely from LDS. No wsum round-trip, x read exactly once (+halo).
// ---------------------------------------------------------------------------
__global__ __launch_bounds__(256) void kBC(const float* __restrict__ x,
        const float* __restrict__ ws_xh, const float* __restrict__ ws_xw,
        const float* __restrict__ ws_asc, const float* __restrict__ ws_aofs,
        const float* __restrict__ ws_wa, float* __restrict__ out)
{
    const int g = blockIdx.x / NB;
    const int band = blockIdx.x - g * NB;
    const int y0 = band * RB;
    const int tid = threadIdx.x;
    const float* gx = x + (size_t)g * CG * HW;
    float* og = out + (size_t)g * CG * HW;

    __shared__ float s_in[CG][RB + 2][LROW];   // 40 KB, data at cols [4..59]
    __shared__ float s_xw[CG][WW];
    __shared__ float s_gh[CG][RB];             // asc[c] * xh[c][y0+r]
    __shared__ float s_wa[CG][9];
    __shared__ float s_bias;

    // phase 0: zero s_in + stage small per-instance data (disjoint arrays)
    {
        float4* z = (float4*)&s_in[0][0][0];
        for (int t = tid; t < CG * (RB + 2) * LROW / 4; t += 256)
            z[t] = make_float4(0.f, 0.f, 0.f, 0.f);
    }
    for (int t = tid; t < CG * WW; t += 256)
        s_xw[t / WW][t - (t / WW) * WW] = ws_xw[(size_t)g * CG * WW + t];
    if (tid < CG * RB) {
        int c = tid / RB, r = tid - (tid / RB) * RB;
        s_gh[c][r] = ws_asc[(size_t)g * CG + c]
                   * ws_xh[(size_t)g * CG * HH + c * HH + y0 + r];
    }
    if (tid >= 64 && tid < 64 + CG * 9) {
        int t = tid - 64;
        s_wa[t / 9][t - (t / 9) * 9] = ws_wa[t];
    }
    if (tid == 63) s_bias = ws_wa[CG * 9] + ws_aofs[g];
    __syncthreads();

    // phase 1: stage band rows y0-1 .. y0+RB (zeros stay for out-of-image)
    for (int t = tid; t < CG * (RB + 2) * (WW / 4); t += 256) {  // 2240
        int c = t / ((RB + 2) * (WW / 4));
        int rem = t - c * ((RB + 2) * (WW / 4));
        int r = rem / (WW / 4), q = rem - r * (WW / 4);
        int ry = y0 - 1 + r;
        if (ry >= 0 && ry < HH) {
            float4 v = *(const float4*)(gx + c * HW + ry * WW + q * 4);
            *(float4*)&s_in[c][r][4 + q * 4] = v;
        }
    }
    __syncthreads();

    // phase 2: conv + epilogue per pixel
    for (int p = tid; p < RB * WW; p += 256) {
        int yl = p / WW, xx = p - yl * WW;
        float acc = s_bias;
        float vx[CG];
        #pragma unroll
        for (int c = 0; c < CG; ++c) {
            const float* r0 = &s_in[c][yl][3 + xx];
            const float* r1 = &s_in[c][yl + 1][3 + xx];
            const float* r2 = &s_in[c][yl + 2][3 + xx];
            const float* wp = s_wa[c];
            float v = r1[1];
            vx[c] = v;
            acc += wp[0] * r0[0] + wp[1] * r0[1] + wp[2] * r0[2]
                 + wp[3] * r1[0] + wp[4] * v     + wp[5] * r1[2]
                 + wp[6] * r2[0] + wp[7] * r2[1] + wp[8] * r2[2];
            acc += s_gh[c][yl] * s_xw[c][xx] * v;
        }
        float sg = 1.f / (1.f + __expf(-acc));
        float* op = og + (y0 + yl) * WW + xx;
        #pragma unroll
        for (int c = 0; c < CG; ++c) op[c * HW] = vx[c] * sg;
    }
}

// ---------------------------------------------------------------------------
extern "C" void kernel_launch(void* const* d_in, const int* in_sizes, int n_in,
                              void* d_out, int out_size, void* d_ws, size_t ws_size,
                              hipStream_t stream)
{
    const float* x    = (const float*)d_in[0];
    const float* w1   = (const float*)d_in[1];
    const float* b1   = (const float*)d_in[2];
    const float* w3   = (const float*)d_in[3];
    const float* b3   = (const float*)d_in[4];
    const float* gn_w = (const float*)d_in[5];
    const float* gn_b = (const float*)d_in[6];
    float* out = (float*)d_out;

    float* ws = (float*)d_ws;
    float* ws_xh   = ws;                                    // BG*CG*HH
    float* ws_xw   = ws_xh + (size_t)BG * CG * HH;          // BG*CG*WW
    float* ws_asc  = ws_xw + (size_t)BG * CG * WW;          // BG*CG
    float* ws_aofs = ws_asc + (size_t)BG * CG;              // BG
    float* ws_wa   = ws_aofs + (size_t)BG;                  // CG*9 + 1

    kA<<<BG, 256, 0, stream>>>(x, w1, b1, w3, b3, gn_w, gn_b,
                               ws_xh, ws_xw, ws_asc, ws_aofs, ws_wa);
    kBC<<<BG * NB, 256, 0, stream>>>(x, ws_xh, ws_xw, ws_asc, ws_aofs,
                                     ws_wa, out);
}

// Round 3
// 498.917 us; speedup vs baseline: 1.6822x; 1.2762x over previous
//
#include <hip/hip_runtime.h>
#include <math.h>

#define GROUPS 32
#define CG 16
#define HH 56
#define WW 56
#define HW (HH*WW)          // 3136
#define BG 1024             // B*GROUPS
#define EPS 1e-5f

#define RB 8                // output rows per band
#define NB 7                // bands per instance (RB*NB == HH)
#define LROW 60             // LDS row stride (floats): cols [0..3]=zero halo, [4..59]=image
#define CSTR (10*LROW)      // 600 floats per channel (10 rows incl. y-halo)
#define PSTR 452            // s_part row stride (floats)

// ---------------------------------------------------------------------------
// Kernel A: fused directional pooling (ONE pass over x) -> 1x1 mix -> gates;
// analytic x2sum; per-channel sum/sumsq of t = gx*xh*xw (second pass over x);
// a2-softmax folded into ws_asc/ws_aofs. Block 0 computes the global
// a1-folded conv weights ws_wa[145].
// ---------------------------------------------------------------------------
__global__ __launch_bounds__(256) void kA(const float* __restrict__ x,
        const float* __restrict__ w1, const float* __restrict__ b1,
        const float* __restrict__ w3, const float* __restrict__ b3,
        const float* __restrict__ gn_w, const float* __restrict__ gn_b,
        float* __restrict__ ws_xh, float* __restrict__ ws_xw,
        float* __restrict__ ws_asc, float* __restrict__ ws_aofs,
        float* __restrict__ ws_wa)
{
    const int g = blockIdx.x;
    const int tid = threadIdx.x;
    const float* gx = x + (size_t)g * CG * HW;

    __shared__ float s_row[CG][HH];   // row means per channel
    __shared__ float s_col[CG][WW];   // col means per channel
    __shared__ float s_xh[CG][HH];    // sigmoid gate over rows
    __shared__ float s_xw[CG][WW];    // sigmoid gate over cols
    __shared__ float ls1[CG], ls2[CG];
    __shared__ float s_x2[CG];

    // one-time: a1-folded conv weights (a1 = softmax(gn_b), same for all g)
    if (g == 0 && tid < CG * 9 + 1) {
        float m = gn_b[0];
        #pragma unroll
        for (int c = 1; c < CG; ++c) m = fmaxf(m, gn_b[c]);
        float a1[CG]; float den = 0.f;
        #pragma unroll
        for (int c = 0; c < CG; ++c) { a1[c] = __expf(gn_b[c] - m); den += a1[c]; }
        float inv = 1.f / den;
        if (tid < CG * 9) {
            int ci = tid / 9, k = tid - (tid / 9) * 9;
            float s = 0.f;
            #pragma unroll
            for (int o = 0; o < CG; ++o) s += a1[o] * w3[(size_t)(o * CG + ci) * 9 + k];
            ws_wa[tid] = s * inv;
        } else {
            float s = 0.f;
            #pragma unroll
            for (int o = 0; o < CG; ++o) s += a1[o] * b3[o];
            ws_wa[CG * 9] = s * inv;
        }
    }

    // fused pooling: 16-lane group per channel, single pass over x.
    // lane q<14 loads float4 of its 4 columns each row; col sums accumulate
    // in registers; row sum reduced across the 16-lane group via shfl.
    {
        const int grp = tid >> 4;       // channel
        const int q   = tid & 15;       // 4-col group (q<14 active)
        const float* pc = gx + grp * HW;
        float c0 = 0.f, c1 = 0.f, c2 = 0.f, c3 = 0.f;
        #pragma unroll 4
        for (int row = 0; row < HH; ++row) {
            float4 v = make_float4(0.f, 0.f, 0.f, 0.f);
            if (q < 14) v = *(const float4*)(pc + row * WW + q * 4);
            c0 += v.x; c1 += v.y; c2 += v.z; c3 += v.w;
            float rs = (v.x + v.y) + (v.z + v.w);
            rs += __shfl_down(rs, 8);
            rs += __shfl_down(rs, 4);
            rs += __shfl_down(rs, 2);
            rs += __shfl_down(rs, 1);
            if (q == 0) s_row[grp][row] = rs * (1.0f / WW);
        }
        if (q < 14) {
            s_col[grp][q * 4 + 0] = c0 * (1.0f / HH);
            s_col[grp][q * 4 + 1] = c1 * (1.0f / HH);
            s_col[grp][q * 4 + 2] = c2 * (1.0f / HH);
            s_col[grp][q * 4 + 3] = c3 * (1.0f / HH);
        }
    }
    __syncthreads();

    // 1x1 conv (16x16 channel mix) + bias + sigmoid
    for (int t = tid; t < 2 * CG * HH; t += 256) {
        int hpart = (t < CG * HH);
        int tt = hpart ? t : t - CG * HH;
        int o = tt / HH, i = tt - (tt / HH) * HH;
        float v = b1[o];
        #pragma unroll
        for (int c = 0; c < CG; ++c)
            v += w1[o * CG + c] * (hpart ? s_row[c][i] : s_col[c][i]);
        float sg = 1.f / (1.f + __expf(-v));
        if (hpart) { s_xh[o][i] = sg; ws_xh[(size_t)g * CG * HH + tt] = sg; }
        else       { s_xw[o][i] = sg; ws_xw[(size_t)g * CG * WW + tt] = sg; }
    }

    // analytic x2sum: thread o computes spatial sum of conv output channel o
    if (tid < CG) {
        ls1[tid] = 0.f; ls2[tid] = 0.f;
        const int o = tid;
        float acc = (float)HW * b3[o];
        for (int c = 0; c < CG; ++c) {
            float S = 0.f;
            #pragma unroll
            for (int r = 0; r < HH; ++r) S += s_row[c][r];
            S *= (float)WW;
            float R0 = (float)WW * s_row[c][HH - 1];
            float R2 = (float)WW * s_row[c][0];
            float C0 = (float)HH * s_col[c][WW - 1];
            float C2 = (float)HH * s_col[c][0];
            const float* p = gx + c * HW;
            float e00 = p[0], e0N = p[WW - 1];
            float eN0 = p[(HH - 1) * WW], eNN = p[(HH - 1) * WW + WW - 1];
            const float* wp = w3 + (size_t)(o * CG + c) * 9;
            #pragma unroll
            for (int dy = 0; dy < 3; ++dy) {
                float Rv = (dy == 0) ? R0 : (dy == 2 ? R2 : 0.f);
                #pragma unroll
                for (int dx = 0; dx < 3; ++dx) {
                    float Cv = (dx == 0) ? C0 : (dx == 2 ? C2 : 0.f);
                    float T = S - Rv - Cv;
                    if (dy != 1 && dx != 1)
                        T += (dy == 0) ? ((dx == 0) ? eNN : eN0)
                                       : ((dx == 0) ? e0N : e00);
                    acc += wp[dy * 3 + dx] * T;
                }
            }
        }
        s_x2[tid] = acc;
    }
    __syncthreads();

    // per-channel sum / sumsq of t = gx * xh * xw (float4, second x pass)
    for (int c = 0; c < CG; ++c) {
        float s1 = 0.f, s2 = 0.f;
        const float4* p = (const float4*)(gx + c * HW);
        for (int idx = tid; idx < HW / 4; idx += 256) {
            int l = idx * 4;
            int yy = l / WW, xb = l - yy * WW;   // 56 % 4 == 0: no row cross
            float4 v = p[idx];
            float xh = s_xh[c][yy];
            float t0 = v.x * xh * s_xw[c][xb];
            float t1 = v.y * xh * s_xw[c][xb + 1];
            float t2 = v.z * xh * s_xw[c][xb + 2];
            float t3 = v.w * xh * s_xw[c][xb + 3];
            s1 += (t0 + t1) + (t2 + t3);
            s2 += (t0 * t0 + t1 * t1) + (t2 * t2 + t3 * t3);
        }
        #pragma unroll
        for (int off = 32; off; off >>= 1) {
            s1 += __shfl_down(s1, off);
            s2 += __shfl_down(s2, off);
        }
        if ((tid & 63) == 0) {
            atomicAdd(&ls1[c], s1);
            atomicAdd(&ls2[c], s2);
        }
    }
    __syncthreads();

    // scale/shift -> fold with a2 = softmax(x2sum/HW)  (lanes 0..15, wave 0)
    if (tid < CG) {
        float mu  = ls1[tid] * (1.0f / HW);
        float var = ls2[tid] * (1.0f / HW) - mu * mu;
        float sc  = gn_w[tid] * rsqrtf(var + EPS);
        float sh  = gn_b[tid] - mu * sc;

        float v2 = s_x2[tid] * (1.0f / HW);
        float m = v2;
        #pragma unroll
        for (int off = 8; off; off >>= 1) m = fmaxf(m, __shfl_xor(m, off));
        float e = __expf(v2 - m);
        float den = e;
        #pragma unroll
        for (int off = 8; off; off >>= 1) den += __shfl_xor(den, off);
        float a2 = e / den;

        ws_asc[(size_t)g * CG + tid] = a2 * sc;
        float part = a2 * sh;
        #pragma unroll
        for (int off = 8; off; off >>= 1) part += __shfl_xor(part, off);
        if (tid == 0) ws_aofs[g] = part;
    }
}

// ---------------------------------------------------------------------------
// Kernel BC: one block per (instance, 8-row band). Stage band in LDS
// (coalesced float4, zero-written halos). Phase 2: 224 strip tasks
// (8 px x 4 channels each) compute conv + gate term with a 10-float
// register sliding window. Partials reduced in LDS; epilogue applies
// bias+sigmoid and writes out = gx * sg.
// ---------------------------------------------------------------------------
__global__ __launch_bounds__(256) void kBC(const float* __restrict__ x,
        const float* __restrict__ ws_xh, const float* __restrict__ ws_xw,
        const float* __restrict__ ws_asc, const float* __restrict__ ws_aofs,
        const float* __restrict__ ws_wa, float* __restrict__ out)
{
    const int g = blockIdx.x / NB;
    const int band = blockIdx.x - g * NB;
    const int y0 = band * RB;
    const int tid = threadIdx.x;
    const float* gx = x + (size_t)g * CG * HW;
    float* og = out + (size_t)g * CG * HW;

    __shared__ float s_in[CG * CSTR];   // 38400 B
    __shared__ float s_part[4 * PSTR];  // 7232 B
    __shared__ float s_xw[CG][WW];      // 3584 B
    __shared__ float s_gh[CG][RB];      // asc[c] * xh[c][y0+r]
    __shared__ float s_wa[CG][9];
    __shared__ float s_bias;

    // phase 0: zero left-halo cols 0..3 of every (c,row); stage small data
    if (tid < CG * (RB + 2)) {
        int c = tid / (RB + 2), r = tid - c * (RB + 2);
        *(float4*)&s_in[c * CSTR + r * LROW] = make_float4(0.f, 0.f, 0.f, 0.f);
    }
    for (int t = tid; t < CG * WW; t += 256)
        s_xw[t / WW][t - (t / WW) * WW] = ws_xw[(size_t)g * CG * WW + t];
    if (tid < CG * RB) {
        int c = tid / RB, r = tid - (tid / RB) * RB;
        s_gh[c][r] = ws_asc[(size_t)g * CG + c]
                   * ws_xh[(size_t)g * CG * HH + c * HH + y0 + r];
    }
    if (tid >= 64 && tid < 64 + CG * 9) {   // FIX: 64+144=208 <= 256 (was 192+144)
        int t = tid - 64;
        s_wa[t / 9][t - (t / 9) * 9] = ws_wa[t];
    }
    if (tid == 0) s_bias = ws_wa[CG * 9] + ws_aofs[g];

    // phase 1: stage rows y0-1 .. y0+RB; write zeros for out-of-image rows
    for (int t = tid; t < CG * (RB + 2) * (WW / 4); t += 256) {   // 2240
        int c = t / ((RB + 2) * (WW / 4));
        int rem = t - c * ((RB + 2) * (WW / 4));
        int r = rem / (WW / 4), q = rem - r * (WW / 4);
        int ry = y0 - 1 + r;
        float4 v = make_float4(0.f, 0.f, 0.f, 0.f);
        if (ry >= 0 && ry < HH)
            v = *(const float4*)(gx + c * HW + ry * WW + q * 4);
        *(float4*)&s_in[c * CSTR + r * LROW + 4 + q * 4] = v;
    }
    __syncthreads();

    // phase 2: strip tasks. t = cgrp*56 + s; s = yl*7 + k; x0 = 8k.
    if (tid < 224) {
        const int cgrp = tid / 56;
        const int s = tid - cgrp * 56;
        const int yl = s / 7;
        const int x0 = (s - yl * 7) * 8;
        // right-edge read: col x0+12, except rightmost strip reads col 0 (zero)
        const int e1c = (x0 < 48) ? (x0 + 12) : 0;
        float acc[8];
        #pragma unroll
        for (int j = 0; j < 8; ++j) acc[j] = 0.f;

        #pragma unroll
        for (int ci = 0; ci < 4; ++ci) {
            const int c = cgrp * 4 + ci;
            const float* base = &s_in[c * CSTR];
            const float* wp = s_wa[c];
            float w0 = wp[0], w1v = wp[1], w2 = wp[2];
            float w3v = wp[3], w4 = wp[4], w5 = wp[5];
            float w6 = wp[6], w7 = wp[7], w8 = wp[8];
            #pragma unroll
            for (int dy = 0; dy < 3; ++dy) {
                const float* rp = base + (yl + dy) * LROW;
                float e0  = rp[x0 + 3];
                float4 V0 = *(const float4*)(rp + x0 + 4);
                float4 V1 = *(const float4*)(rp + x0 + 8);
                float e1  = rp[e1c];
                float win[10] = {e0, V0.x, V0.y, V0.z, V0.w,
                                 V1.x, V1.y, V1.z, V1.w, e1};
                float a0 = (dy == 0) ? w0 : ((dy == 1) ? w3v : w6);
                float a1 = (dy == 0) ? w1v : ((dy == 1) ? w4 : w7);
                float a2 = (dy == 0) ? w2 : ((dy == 1) ? w5 : w8);
                #pragma unroll
                for (int j = 0; j < 8; ++j)
                    acc[j] += a0 * win[j] + a1 * win[j + 1] + a2 * win[j + 2];
                if (dy == 1) {   // gate term on center row values
                    float gh = s_gh[c][yl];
                    float4 X0 = *(const float4*)(&s_xw[c][x0]);
                    float4 X1 = *(const float4*)(&s_xw[c][x0 + 4]);
                    float xwv[8] = {X0.x, X0.y, X0.z, X0.w,
                                    X1.x, X1.y, X1.z, X1.w};
                    #pragma unroll
                    for (int j = 0; j < 8; ++j)
                        acc[j] += gh * xwv[j] * win[j + 1];
                }
            }
        }
        float* pp = &s_part[cgrp * PSTR + yl * WW + x0];
        *(float4*)pp       = make_float4(acc[0], acc[1], acc[2], acc[3]);
        *(float4*)(pp + 4) = make_float4(acc[4], acc[5], acc[6], acc[7]);
    }
    __syncthreads();

    // phase 3: reduce partials + sigmoid + write out
    for (int p = tid; p < RB * WW; p += 256) {
        int yl = p / WW, xx = p - yl * WW;
        float a = s_bias + s_part[p] + s_part[PSTR + p]
                + s_part[2 * PSTR + p] + s_part[3 * PSTR + p];
        float sg = 1.f / (1.f + __expf(-a));
        const float* ctr = &s_in[(yl + 1) * LROW + 4 + xx];
        float* op = og + (y0 + yl) * WW + xx;
        #pragma unroll
        for (int c = 0; c < CG; ++c)
            op[c * HW] = ctr[c * CSTR] * sg;
    }
}

// ---------------------------------------------------------------------------
extern "C" void kernel_launch(void* const* d_in, const int* in_sizes, int n_in,
                              void* d_out, int out_size, void* d_ws, size_t ws_size,
                              hipStream_t stream)
{
    const float* x    = (const float*)d_in[0];
    const float* w1   = (const float*)d_in[1];
    const float* b1   = (const float*)d_in[2];
    const float* w3   = (const float*)d_in[3];
    const float* b3   = (const float*)d_in[4];
    const float* gn_w = (const float*)d_in[5];
    const float* gn_b = (const float*)d_in[6];
    float* out = (float*)d_out;

    float* ws = (float*)d_ws;
    float* ws_xh   = ws;                                    // BG*CG*HH
    float* ws_xw   = ws_xh + (size_t)BG * CG * HH;          // BG*CG*WW
    float* ws_asc  = ws_xw + (size_t)BG * CG * WW;          // BG*CG
    float* ws_aofs = ws_asc + (size_t)BG * CG;              // BG
    float* ws_wa   = ws_aofs + (size_t)BG;                  // CG*9 + 1

    kA<<<BG, 256, 0, stream>>>(x, w1, b1, w3, b3, gn_w, gn_b,
                               ws_xh, ws_xw, ws_asc, ws_aofs, ws_wa);
    kBC<<<BG * NB, 256, 0, stream>>>(x, ws_xh, ws_xw, ws_asc, ws_aofs,
                                     ws_wa, out);
}

// Round 4
// 485.414 us; speedup vs baseline: 1.7290x; 1.0278x over previous
//
#include <hip/hip_runtime.h>
#include <math.h>

#define GROUPS 32
#define CG 16
#define HH 56
#define WW 56
#define HW (HH*WW)          // 3136
#define BG 1024             // B*GROUPS
#define EPS 1e-5f

#define RB 4                // output rows per band
#define NB 14               // bands per instance (RB*NB == HH)
#define NR (RB+2)           // staged rows incl. halo = 6
#define LROW 60             // LDS row stride (floats): cols [0..3]=zero halo, [4..59]=image
#define CSTR (NR*LROW)      // 360 floats per channel
#define PSTR 228            // s_part row stride (floats, %32=4 for bank spread)

// ---------------------------------------------------------------------------
// Kernel A: fused directional pooling (ONE pass over x) -> 1x1 mix -> gates;
// analytic x2sum (per-c stats staged in LDS, 256-thread tap partials);
// per-channel sum/sumsq via 16-lane-group-per-channel register accumulation
// (8 shfls total, no atomics); a2-softmax folded into ws_asc/ws_aofs.
// Block 0 computes the global a1-folded conv weights ws_wa[145].
// ---------------------------------------------------------------------------
__global__ __launch_bounds__(256) void kA(const float* __restrict__ x,
        const float* __restrict__ w1, const float* __restrict__ b1,
        const float* __restrict__ w3, const float* __restrict__ b3,
        const float* __restrict__ gn_w, const float* __restrict__ gn_b,
        float* __restrict__ ws_xh, float* __restrict__ ws_xw,
        float* __restrict__ ws_asc, float* __restrict__ ws_aofs,
        float* __restrict__ ws_wa)
{
    const int g = blockIdx.x;
    const int tid = threadIdx.x;
    const float* gx = x + (size_t)g * CG * HW;

    __shared__ float s_row[CG][HH];   // row means per channel
    __shared__ float s_col[CG][WW];   // col means per channel
    __shared__ float s_xh[CG][HH];    // sigmoid gate over rows
    __shared__ float s_xw[CG][WW];    // sigmoid gate over cols
    __shared__ float s_st[CG][9];     // S,R0,R2,C0,C2,e00,e0N,eN0,eNN
    __shared__ float s_x2p[CG][CG];   // x2 partials [c][o]
    __shared__ float ls1[CG], ls2[CG];

    // one-time: a1-folded conv weights (a1 = softmax(gn_b), same for all g)
    if (g == 0 && tid < CG * 9 + 1) {
        float m = gn_b[0];
        #pragma unroll
        for (int c = 1; c < CG; ++c) m = fmaxf(m, gn_b[c]);
        float a1[CG]; float den = 0.f;
        #pragma unroll
        for (int c = 0; c < CG; ++c) { a1[c] = __expf(gn_b[c] - m); den += a1[c]; }
        float inv = 1.f / den;
        if (tid < CG * 9) {
            int ci = tid / 9, k = tid - (tid / 9) * 9;
            float s = 0.f;
            #pragma unroll
            for (int o = 0; o < CG; ++o) s += a1[o] * w3[(size_t)(o * CG + ci) * 9 + k];
            ws_wa[tid] = s * inv;
        } else {
            float s = 0.f;
            #pragma unroll
            for (int o = 0; o < CG; ++o) s += a1[o] * b3[o];
            ws_wa[CG * 9] = s * inv;
        }
    }

    // fused pooling: 16-lane group per channel, single pass over x.
    {
        const int grp = tid >> 4;       // channel
        const int q   = tid & 15;       // 4-col group (q<14 active)
        const float* pc = gx + grp * HW;
        float c0 = 0.f, c1 = 0.f, c2 = 0.f, c3 = 0.f;
        #pragma unroll 4
        for (int row = 0; row < HH; ++row) {
            float4 v = make_float4(0.f, 0.f, 0.f, 0.f);
            if (q < 14) v = *(const float4*)(pc + row * WW + q * 4);
            c0 += v.x; c1 += v.y; c2 += v.z; c3 += v.w;
            float rs = (v.x + v.y) + (v.z + v.w);
            rs += __shfl_down(rs, 8);
            rs += __shfl_down(rs, 4);
            rs += __shfl_down(rs, 2);
            rs += __shfl_down(rs, 1);
            if (q == 0) s_row[grp][row] = rs * (1.0f / WW);
        }
        if (q < 14) {
            s_col[grp][q * 4 + 0] = c0 * (1.0f / HH);
            s_col[grp][q * 4 + 1] = c1 * (1.0f / HH);
            s_col[grp][q * 4 + 2] = c2 * (1.0f / HH);
            s_col[grp][q * 4 + 3] = c3 * (1.0f / HH);
        }
    }
    __syncthreads();   // S1

    // 1x1 conv (16x16 channel mix) + bias + sigmoid
    for (int t = tid; t < 2 * CG * HH; t += 256) {
        int hpart = (t < CG * HH);
        int tt = hpart ? t : t - CG * HH;
        int o = tt / HH, i = tt - (tt / HH) * HH;
        float v = b1[o];
        #pragma unroll
        for (int c = 0; c < CG; ++c)
            v += w1[o * CG + c] * (hpart ? s_row[c][i] : s_col[c][i]);
        float sg = 1.f / (1.f + __expf(-v));
        if (hpart) { s_xh[o][i] = sg; ws_xh[(size_t)g * CG * HH + tt] = sg; }
        else       { s_xw[o][i] = sg; ws_xw[(size_t)g * CG * WW + tt] = sg; }
    }

    // stage per-channel stats for the analytic x2sum (threads 0..15)
    if (tid < CG) {
        const int c = tid;
        float S = 0.f;
        #pragma unroll
        for (int r = 0; r < HH; ++r) S += s_row[c][r];
        s_st[c][0] = S * (float)WW;
        s_st[c][1] = (float)WW * s_row[c][HH - 1];   // R0 (dy=0 excluded row)
        s_st[c][2] = (float)WW * s_row[c][0];        // R2
        s_st[c][3] = (float)HH * s_col[c][WW - 1];   // C0
        s_st[c][4] = (float)HH * s_col[c][0];        // C2
        const float* p = gx + c * HW;
        s_st[c][5] = p[0];                           // e00
        s_st[c][6] = p[WW - 1];                      // e0N
        s_st[c][7] = p[(HH - 1) * WW];               // eN0
        s_st[c][8] = p[(HH - 1) * WW + WW - 1];      // eNN
    }
    __syncthreads();   // S2

    // x2 tap partials: thread (o = tid>>4, c = tid&15)
    {
        const int o = tid >> 4, c = tid & 15;
        const float* wp = w3 + (size_t)(o * CG + c) * 9;
        const float* st = s_st[c];
        float S = st[0];
        float acc = 0.f;
        #pragma unroll
        for (int dy = 0; dy < 3; ++dy) {
            float Rv = (dy == 0) ? st[1] : (dy == 2 ? st[2] : 0.f);
            #pragma unroll
            for (int dx = 0; dx < 3; ++dx) {
                float Cv = (dx == 0) ? st[3] : (dx == 2 ? st[4] : 0.f);
                float T = S - Rv - Cv;
                if (dy != 1 && dx != 1)
                    T += (dy == 0) ? ((dx == 0) ? st[8] : st[7])
                                   : ((dx == 0) ? st[6] : st[5]);
                acc += wp[dy * 3 + dx] * T;
            }
        }
        s_x2p[c][o] = acc;
    }

    // per-channel sum/sumsq of t = gx*xh*xw: 16-lane group per channel,
    // register accumulation, ONE 4-level shfl reduce, direct store.
    {
        const int c = tid >> 4;
        const int q = tid & 15;
        float s1 = 0.f, s2 = 0.f;
        if (q < 14) {
            const float* pc = gx + c * HW;
            float xw0 = s_xw[c][q * 4 + 0], xw1 = s_xw[c][q * 4 + 1];
            float xw2 = s_xw[c][q * 4 + 2], xw3v = s_xw[c][q * 4 + 3];
            #pragma unroll 4
            for (int row = 0; row < HH; ++row) {
                float4 v = *(const float4*)(pc + row * WW + q * 4);
                float xh = s_xh[c][row];
                float t0 = v.x * xh * xw0;
                float t1 = v.y * xh * xw1;
                float t2 = v.z * xh * xw2;
                float t3 = v.w * xh * xw3v;
                s1 += (t0 + t1) + (t2 + t3);
                s2 += (t0 * t0 + t1 * t1) + (t2 * t2 + t3 * t3);
            }
        }
        s1 += __shfl_down(s1, 8);  s2 += __shfl_down(s2, 8);
        s1 += __shfl_down(s1, 4);  s2 += __shfl_down(s2, 4);
        s1 += __shfl_down(s1, 2);  s2 += __shfl_down(s2, 2);
        s1 += __shfl_down(s1, 1);  s2 += __shfl_down(s2, 1);
        if (q == 0) { ls1[c] = s1; ls2[c] = s2; }
    }
    __syncthreads();   // S3

    // finalize (lanes 0..15): x2 reduce, scale/shift, a2 softmax, fold
    if (tid < CG) {
        const int o = tid;
        float x2 = (float)HW * b3[o];
        #pragma unroll
        for (int c = 0; c < CG; ++c) x2 += s_x2p[c][o];

        float mu  = ls1[o] * (1.0f / HW);
        float var = ls2[o] * (1.0f / HW) - mu * mu;
        float sc  = gn_w[o] * rsqrtf(var + EPS);
        float sh  = gn_b[o] - mu * sc;

        float v2 = x2 * (1.0f / HW);
        float m = v2;
        #pragma unroll
        for (int off = 8; off; off >>= 1) m = fmaxf(m, __shfl_xor(m, off));
        float e = __expf(v2 - m);
        float den = e;
        #pragma unroll
        for (int off = 8; off; off >>= 1) den += __shfl_xor(den, off);
        float a2 = e / den;

        ws_asc[(size_t)g * CG + o] = a2 * sc;
        float part = a2 * sh;
        #pragma unroll
        for (int off = 8; off; off >>= 1) part += __shfl_xor(part, off);
        if (o == 0) ws_aofs[g] = part;
    }
}

// ---------------------------------------------------------------------------
// Kernel BC: one block per (instance, 4-row band). LDS ~35 KB -> 4 blocks/CU
// (was 50.7 KB -> 2.5). Phase 2: 224 strip tasks (8 px x 2 channels each),
// 10-float register sliding window. Phase 3: float4 epilogue (4 px x 4 ch
// per thread), partials read as float4, float4 global stores.
// ---------------------------------------------------------------------------
__global__ __launch_bounds__(256) void kBC(const float* __restrict__ x,
        const float* __restrict__ ws_xh, const float* __restrict__ ws_xw,
        const float* __restrict__ ws_asc, const float* __restrict__ ws_aofs,
        const float* __restrict__ ws_wa, float* __restrict__ out)
{
    const int g = blockIdx.x / NB;
    const int band = blockIdx.x - g * NB;
    const int y0 = band * RB;
    const int tid = threadIdx.x;
    const float* gx = x + (size_t)g * CG * HW;
    float* og = out + (size_t)g * CG * HW;

    __shared__ float s_in[CG * CSTR];   // 16*360*4 = 23040 B
    __shared__ float s_part[8 * PSTR];  // 8*228*4  =  7296 B
    __shared__ float s_xw[CG][WW];      //            3584 B
    __shared__ float s_gh[CG][RB];      // asc[c] * xh[c][y0+r]
    __shared__ float s_wa[CG][9];
    __shared__ float s_bias;

    // phase 0: zero left-halo cols 0..3 of every (c,row); stage small data
    if (tid < CG * NR) {                         // 96 tasks
        int c = tid / NR, r = tid - c * NR;
        *(float4*)&s_in[c * CSTR + r * LROW] = make_float4(0.f, 0.f, 0.f, 0.f);
    }
    for (int t = tid; t < CG * WW; t += 256)
        s_xw[t / WW][t - (t / WW) * WW] = ws_xw[(size_t)g * CG * WW + t];
    if (tid < CG * RB) {                         // 64 tasks
        int c = tid / RB, r = tid - (tid / RB) * RB;
        s_gh[c][r] = ws_asc[(size_t)g * CG + c]
                   * ws_xh[(size_t)g * CG * HH + c * HH + y0 + r];
    }
    if (tid >= 96 && tid < 96 + CG * 9) {        // 96+144 = 240 <= 256
        int t = tid - 96;
        s_wa[t / 9][t - (t / 9) * 9] = ws_wa[t];
    }
    if (tid == 240) s_bias = ws_wa[CG * 9] + ws_aofs[g];

    // phase 1: stage rows y0-1 .. y0+RB; zeros for out-of-image rows
    for (int t = tid; t < CG * NR * (WW / 4); t += 256) {   // 1344
        int c = t / (NR * (WW / 4));
        int rem = t - c * (NR * (WW / 4));
        int r = rem / (WW / 4), q = rem - r * (WW / 4);
        int ry = y0 - 1 + r;
        float4 v = make_float4(0.f, 0.f, 0.f, 0.f);
        if (ry >= 0 && ry < HH)
            v = *(const float4*)(gx + c * HW + ry * WW + q * 4);
        *(float4*)&s_in[c * CSTR + r * LROW + 4 + q * 4] = v;
    }
    __syncthreads();

    // phase 2: strip tasks. tid<224: cgrp = tid/28 (2 ch), s = tid%28.
    if (tid < 224) {
        const int cgrp = tid / 28;
        const int s = tid - cgrp * 28;
        const int yl = s / 7;
        const int x0 = (s - yl * 7) * 8;
        const int e1c = (x0 < 48) ? (x0 + 12) : 0;   // rightmost reads zero halo
        float acc[8];
        #pragma unroll
        for (int j = 0; j < 8; ++j) acc[j] = 0.f;

        #pragma unroll
        for (int ci = 0; ci < 2; ++ci) {
            const int c = cgrp * 2 + ci;
            const float* base = &s_in[c * CSTR];
            const float* wp = s_wa[c];
            float w0 = wp[0], w1v = wp[1], w2 = wp[2];
            float w3v = wp[3], w4 = wp[4], w5 = wp[5];
            float w6 = wp[6], w7 = wp[7], w8 = wp[8];
            #pragma unroll
            for (int dy = 0; dy < 3; ++dy) {
                const float* rp = base + (yl + dy) * LROW;
                float e0  = rp[x0 + 3];
                float4 V0 = *(const float4*)(rp + x0 + 4);
                float4 V1 = *(const float4*)(rp + x0 + 8);
                float e1  = rp[e1c];
                float win[10] = {e0, V0.x, V0.y, V0.z, V0.w,
                                 V1.x, V1.y, V1.z, V1.w, e1};
                float a0 = (dy == 0) ? w0 : ((dy == 1) ? w3v : w6);
                float a1 = (dy == 0) ? w1v : ((dy == 1) ? w4 : w7);
                float a2 = (dy == 0) ? w2 : ((dy == 1) ? w5 : w8);
                #pragma unroll
                for (int j = 0; j < 8; ++j)
                    acc[j] += a0 * win[j] + a1 * win[j + 1] + a2 * win[j + 2];
                if (dy == 1) {   // gate term on center row values
                    float gh = s_gh[c][yl];
                    float4 X0 = *(const float4*)(&s_xw[c][x0]);
                    float4 X1 = *(const float4*)(&s_xw[c][x0 + 4]);
                    float xwv[8] = {X0.x, X0.y, X0.z, X0.w,
                                    X1.x, X1.y, X1.z, X1.w};
                    #pragma unroll
                    for (int j = 0; j < 8; ++j)
                        acc[j] += gh * xwv[j] * win[j + 1];
                }
            }
        }
        float* pp = &s_part[cgrp * PSTR + yl * WW + x0];
        *(float4*)pp       = make_float4(acc[0], acc[1], acc[2], acc[3]);
        *(float4*)(pp + 4) = make_float4(acc[4], acc[5], acc[6], acc[7]);
    }
    __syncthreads();

    // phase 3: float4 epilogue. tid<224: cg2 = tid/56 (4 channels each),
    // qd = tid%56 -> (yl = qd/14, xq = qd%14) pixel quad.
    if (tid < 224) {
        const int cg2 = tid / 56;
        const int qd = tid - cg2 * 56;
        const int yl = qd / 14;
        const int xq = qd - yl * 14;
        const int po = yl * WW + xq * 4;

        float4 a = make_float4(s_bias, s_bias, s_bias, s_bias);
        #pragma unroll
        for (int cg = 0; cg < 8; ++cg) {
            float4 pv = *(const float4*)&s_part[cg * PSTR + po];
            a.x += pv.x; a.y += pv.y; a.z += pv.z; a.w += pv.w;
        }
        float4 sg;
        sg.x = 1.f / (1.f + __expf(-a.x));
        sg.y = 1.f / (1.f + __expf(-a.y));
        sg.z = 1.f / (1.f + __expf(-a.z));
        sg.w = 1.f / (1.f + __expf(-a.w));

        const int coff = (yl + 1) * LROW + 4 + xq * 4;
        float* ob = og + (y0 + yl) * WW + xq * 4;
        #pragma unroll
        for (int ci = 0; ci < 4; ++ci) {
            const int c = cg2 * 4 + ci;
            float4 v = *(const float4*)&s_in[c * CSTR + coff];
            float4 o4 = make_float4(v.x * sg.x, v.y * sg.y,
                                    v.z * sg.z, v.w * sg.w);
            *(float4*)(ob + c * HW) = o4;
        }
    }
}

// ---------------------------------------------------------------------------
extern "C" void kernel_launch(void* const* d_in, const int* in_sizes, int n_in,
                              void* d_out, int out_size, void* d_ws, size_t ws_size,
                              hipStream_t stream)
{
    const float* x    = (const float*)d_in[0];
    const float* w1   = (const float*)d_in[1];
    const float* b1   = (const float*)d_in[2];
    const float* w3   = (const float*)d_in[3];
    const float* b3   = (const float*)d_in[4];
    const float* gn_w = (const float*)d_in[5];
    const float* gn_b = (const float*)d_in[6];
    float* out = (float*)d_out;

    float* ws = (float*)d_ws;
    float* ws_xh   = ws;                                    // BG*CG*HH
    float* ws_xw   = ws_xh + (size_t)BG * CG * HH;          // BG*CG*WW
    float* ws_asc  = ws_xw + (size_t)BG * CG * WW;          // BG*CG
    float* ws_aofs = ws_asc + (size_t)BG * CG;              // BG
    float* ws_wa   = ws_aofs + (size_t)BG;                  // CG*9 + 1

    kA<<<BG, 256, 0, stream>>>(x, w1, b1, w3, b3, gn_w, gn_b,
                               ws_xh, ws_xw, ws_asc, ws_aofs, ws_wa);
    kBC<<<BG * NB, 256, 0, stream>>>(x, ws_xh, ws_xw, ws_asc, ws_aofs,
                                     ws_wa, out);
}